// Round 10
// baseline (207.988 us; speedup 1.0000x reference)
//
#include <hip/hip_runtime.h>
#include <hip/hip_bf16.h>

#define EPSV 1e-3f

__device__ __forceinline__ float rcp_fast(float x){ return __builtin_amdgcn_rcpf(x); }
__device__ __forceinline__ float sigm(float x){ return rcp_fast(1.f + __expf(-x)); }
__device__ __forceinline__ float tanh_fast(float x){
    float e = __expf(2.f * x);
    return 1.f - 2.f * rcp_fast(e + 1.f);
}

// 8-lane-group broadcast: src_lane = (lane & 0x18) | K
template<int K>
__device__ __forceinline__ float bc8(float v){
    return __int_as_float(__builtin_amdgcn_ds_swizzle(__float_as_int(v), (K << 5) | 0x18));
}
#define BC8_ALL(dst, src) do { \
    dst[0]=bc8<0>(src); dst[1]=bc8<1>(src); dst[2]=bc8<2>(src); dst[3]=bc8<3>(src); \
    dst[4]=bc8<4>(src); dst[5]=bc8<5>(src); dst[6]=bc8<6>(src); dst[7]=bc8<7>(src); } while(0)

// ---------------- K1: stage-1 LSTM, two-phase (x@W GEMM + recurrence) --------
// R9 lesson: 24 ds_read_b128/lane-step = 4 B/FMA -> LDS-pipe-bound (123us model
// == 126us measured). Fix: phase A lane owns ONE gate col (W = 16 regs, no
// remat pressure) computing ZX=x@W0+b into LDS z-tiles; phase B lane=(s,d)
// holds U quad-slice (32 regs) and reads 4 z-scalars/step. 4-t chunks,
// double-buffered: phase A of chunk c+1 overlaps recurrence of chunk c.
__global__ __launch_bounds__(256)
__attribute__((amdgpu_waves_per_eu(1, 4)))
void k1_lstm0(
    const float* __restrict__ noise, const float* __restrict__ W0,
    const float* __restrict__ U0, const float* __restrict__ b0,
    float* __restrict__ Hbuf, float* __restrict__ Cbuf, double* __restrict__ stats1)
{
    __shared__ float wbuf[16*33];      // [f][col], stride 33
    __shared__ float ubufT[8*36];      // [d][e*4+g] (144B slices, 16B-aligned)
    __shared__ float bbuf[32];
    __shared__ float zbuf[2][32*132];  // [buf][s_local*132 + t'*33 + col]
    __shared__ float red[4][4][8];

    const int tid = threadIdx.x;
    // stage weights (512 wbuf entries over 256 threads: 2 each)
    {
        const int i0 = tid,        f0 = i0 >> 5, c0 = i0 & 31;
        const int i1 = tid + 256,  f1 = i1 >> 5, c1 = i1 & 31;
        wbuf[f0*33 + c0] = W0[f0*32 + c0];
        wbuf[f1*33 + c1] = W0[f1*32 + c1];
        const int dd = tid & 7, eg = tid >> 3, e = eg >> 2, g = eg & 3;
        ubufT[dd*36 + eg] = U0[e*32 + 8*g + dd];
        if (tid < 32) bbuf[tid] = b0[tid];
    }
    __syncthreads();

    const int col = tid & 31;          // phase-A role
    const int j   = tid >> 5;          // 0..7
    const int d   = tid & 7;           // phase-B role
    const int sB  = tid >> 3;          // 0..31
    const size_t sampleBase = (size_t)blockIdx.x * 32;

    float wcol[16];
    #pragma unroll
    for (int f = 0; f < 16; ++f) wcol[f] = wbuf[f*33 + col];
    const float bcol = bbuf[col];
    float4 uq[8];
    #pragma unroll
    for (int e = 0; e < 8; ++e) uq[e] = *reinterpret_cast<const float4*>(&ubufT[d*36 + e*4]);

#define PHASE_A(CK, BUF) do {                                                     \
    _Pragma("unroll 1")                                                           \
    for (int k = 0; k < 4; ++k){                                                  \
        const int sl = k*8 + j;                                                   \
        const float4* xp = reinterpret_cast<const float4*>(                       \
            noise + (sampleBase + sl)*512 + (CK)*64);                             \
        float* zw = &zbuf[BUF][sl*132 + col];                                     \
        _Pragma("unroll")                                                         \
        for (int tp = 0; tp < 4; ++tp){                                           \
            float4 q0 = xp[tp*4+0], q1 = xp[tp*4+1], q2 = xp[tp*4+2], q3 = xp[tp*4+3]; \
            float z = bcol;                                                       \
            z = fmaf(q0.x, wcol[0], z);  z = fmaf(q0.y, wcol[1], z);              \
            z = fmaf(q0.z, wcol[2], z);  z = fmaf(q0.w, wcol[3], z);              \
            z = fmaf(q1.x, wcol[4], z);  z = fmaf(q1.y, wcol[5], z);              \
            z = fmaf(q1.z, wcol[6], z);  z = fmaf(q1.w, wcol[7], z);              \
            z = fmaf(q2.x, wcol[8], z);  z = fmaf(q2.y, wcol[9], z);              \
            z = fmaf(q2.z, wcol[10], z); z = fmaf(q2.w, wcol[11], z);             \
            z = fmaf(q3.x, wcol[12], z); z = fmaf(q3.y, wcol[13], z);             \
            z = fmaf(q3.z, wcol[14], z); z = fmaf(q3.w, wcol[15], z);             \
            zw[tp*33] = z;                                                        \
        }                                                                         \
    }                                                                             \
} while(0)

    float h = 0.f, c = 0.f, hall[8];
    #pragma unroll
    for (int e = 0; e < 8; ++e) hall[e] = 0.f;

    PHASE_A(0, 0);
    __syncthreads();

    #pragma unroll 1
    for (int ck = 0; ck < 8; ++ck){
        if (ck < 7) PHASE_A(ck + 1, (ck + 1) & 1);
        const float* zs = &zbuf[ck & 1][sB*132 + d];
        #pragma unroll
        for (int tp = 0; tp < 4; ++tp){
            float z0 = zs[tp*33], z1 = zs[tp*33 + 8], z2 = zs[tp*33 + 16], z3 = zs[tp*33 + 24];
            #pragma unroll
            for (int e = 0; e < 8; ++e){
                z0 = fmaf(hall[e], uq[e].x, z0); z1 = fmaf(hall[e], uq[e].y, z1);
                z2 = fmaf(hall[e], uq[e].z, z2); z3 = fmaf(hall[e], uq[e].w, z3);
            }
            c = fmaf(sigm(z1), c, sigm(z0) * tanh_fast(z2));
            h = sigm(z3) * tanh_fast(c);
            BC8_ALL(hall, h);
        }
        __syncthreads();
    }
#undef PHASE_A

    Hbuf[(size_t)blockIdx.x*256 + tid] = h;   // lane (sB,d) -> (base+sB)*8+d
    Cbuf[(size_t)blockIdx.x*256 + tid] = c;

    float v0 = h, v1 = h*h, v2 = c, v3 = c*c;
    v0 += __shfl_down(v0,32); v0 += __shfl_down(v0,16); v0 += __shfl_down(v0,8);
    v1 += __shfl_down(v1,32); v1 += __shfl_down(v1,16); v1 += __shfl_down(v1,8);
    v2 += __shfl_down(v2,32); v2 += __shfl_down(v2,16); v2 += __shfl_down(v2,8);
    v3 += __shfl_down(v3,32); v3 += __shfl_down(v3,16); v3 += __shfl_down(v3,8);
    const int w = tid >> 6;
    if ((tid & 63) < 8){ red[0][w][d]=v0; red[1][w][d]=v1; red[2][w][d]=v2; red[3][w][d]=v3; }
    __syncthreads();
    if (tid < 32){
        const int s = tid >> 3, dd = tid & 7;
        float acc = red[s][0][dd] + red[s][1][dd] + red[s][2][dd] + red[s][3][dd];
        atomicAdd(stats1 + s*8 + dd, (double)acc);
    }
}

// ---------------- K2: BN1-apply + 14-step AR LSTM (relu), BN3 sums -----------
__global__ __launch_bounds__(256) void k2_ar(
    const float* __restrict__ Hbuf, const float* __restrict__ Cbuf,
    const double* __restrict__ stats1,
    const float* __restrict__ gamma_h, const float* __restrict__ beta_h,
    const float* __restrict__ gamma_c, const float* __restrict__ beta_c,
    const float* __restrict__ W1, const float* __restrict__ U1, const float* __restrict__ b1,
    double* __restrict__ stats3, int B)
{
    __shared__ float ls[8*36];
    __shared__ float red[2][4][8];
    const int tid = threadIdx.x;
    const int d = tid & 7;
    {
        const int dd = tid & 7, eg = tid >> 3, e = eg >> 2, g = eg & 3;
        ls[dd*36 + eg] = W1[e*32 + 8*g + dd] + U1[e*32 + 8*g + dd];
    }
    const double invB = 1.0 / (double)B;
    const float meanH = (float)(stats1[d]      * invB);
    const float eH2   = (float)(stats1[8 + d]  * invB);
    const float meanC = (float)(stats1[16 + d] * invB);
    const float eC2   = (float)(stats1[24 + d] * invB);
    const float aH = gamma_h[d] * rsqrtf(eH2 - meanH*meanH + EPSV);
    const float aC = gamma_c[d] * rsqrtf(eC2 - meanC*meanC + EPSV);
    float h = fmaf(Hbuf[(size_t)blockIdx.x*256 + tid], aH, beta_h[d] - meanH*aH);
    float c = fmaf(Cbuf[(size_t)blockIdx.x*256 + tid], aC, beta_c[d] - meanC*aC);
    float bcv[4];
    #pragma unroll
    for (int g = 0; g < 4; ++g) bcv[g] = b1[8*g + d];
    __syncthreads();
    const float* sp = &ls[d*36];

    float s1 = 0.f, s2 = 0.f;
    #pragma unroll
    for (int r = 0; r < 14; ++r){
        float hall[8]; BC8_ALL(hall, h);
        float z0 = bcv[0], z1 = bcv[1], z2 = bcv[2], z3 = bcv[3];
        #pragma unroll
        for (int e = 0; e < 8; ++e){
            const float4 u = *reinterpret_cast<const float4*>(sp + e*4);
            z0 = fmaf(hall[e], u.x, z0); z1 = fmaf(hall[e], u.y, z1);
            z2 = fmaf(hall[e], u.z, z2); z3 = fmaf(hall[e], u.w, z3);
        }
        c = fmaf(sigm(z1), c, sigm(z0) * fmaxf(z2, 0.f));
        h = sigm(z3) * fmaxf(c, 0.f);
        s1 += h; s2 = fmaf(h, h, s2);
    }
    s1 += __shfl_down(s1,32); s1 += __shfl_down(s1,16); s1 += __shfl_down(s1,8);
    s2 += __shfl_down(s2,32); s2 += __shfl_down(s2,16); s2 += __shfl_down(s2,8);
    const int w = tid >> 6;
    if ((tid & 63) < 8){ red[0][w][d] = s1; red[1][w][d] = s2; }
    __syncthreads();
    if (tid < 16){
        const int s = tid >> 3, dd = tid & 7;
        float acc = red[s][0][dd] + red[s][1][dd] + red[s][2][dd] + red[s][3][dd];
        atomicAdd(stats3 + s*8 + dd, (double)acc);
    }
}

// ---------------- K3: AR replay + BN3 + output LSTM (8->4) -------------------
__global__ __launch_bounds__(256) void k3_out(
    const float* __restrict__ Hbuf, const float* __restrict__ Cbuf,
    const double* __restrict__ stats1, const double* __restrict__ stats3,
    const float* __restrict__ gamma_h, const float* __restrict__ beta_h,
    const float* __restrict__ gamma_c, const float* __restrict__ beta_c,
    const float* __restrict__ W1, const float* __restrict__ U1, const float* __restrict__ b1,
    const float* __restrict__ gamma3, const float* __restrict__ beta3,
    const float* __restrict__ W2, const float* __restrict__ U2, const float* __restrict__ b2,
    float* __restrict__ out, int B)
{
    __shared__ float ls[8*36];
    __shared__ float lw2[4*36];
    __shared__ float lu2[4*20];
    const int tid = threadIdx.x;
    const int d = tid & 7;
    {
        const int dd = tid & 7, eg = tid >> 3, e = eg >> 2, g = eg & 3;
        ls[dd*36 + eg] = W1[e*32 + 8*g + dd] + U1[e*32 + 8*g + dd];
    }
    if (tid < 128){
        const int qq = tid & 3, eg = tid >> 2, e = eg >> 2, g = eg & 3;
        lw2[qq*36 + eg] = W2[e*16 + 4*g + qq];
    }
    if (tid < 64){
        const int qq = tid & 3, eg = tid >> 2, e = eg >> 2, g = eg & 3;
        lu2[qq*20 + eg] = U2[e*16 + 4*g + qq];
    }
    const double invB = 1.0 / (double)B;
    const float meanH = (float)(stats1[d]      * invB);
    const float eH2   = (float)(stats1[8 + d]  * invB);
    const float meanC = (float)(stats1[16 + d] * invB);
    const float eC2   = (float)(stats1[24 + d] * invB);
    const float aH = gamma_h[d] * rsqrtf(eH2 - meanH*meanH + EPSV);
    const float aC = gamma_c[d] * rsqrtf(eC2 - meanC*meanC + EPSV);
    float h = fmaf(Hbuf[(size_t)blockIdx.x*256 + tid], aH, beta_h[d] - meanH*aH);
    float c = fmaf(Cbuf[(size_t)blockIdx.x*256 + tid], aC, beta_c[d] - meanC*aC);
    float bcv[4];
    #pragma unroll
    for (int g = 0; g < 4; ++g) bcv[g] = b1[8*g + d];
    __syncthreads();
    const float* sp = &ls[d*36];

    float barh[14];
    #pragma unroll
    for (int r = 0; r < 14; ++r){
        float hall[8]; BC8_ALL(hall, h);
        float z0 = bcv[0], z1 = bcv[1], z2 = bcv[2], z3 = bcv[3];
        #pragma unroll
        for (int e = 0; e < 8; ++e){
            const float4 u = *reinterpret_cast<const float4*>(sp + e*4);
            z0 = fmaf(hall[e], u.x, z0); z1 = fmaf(hall[e], u.y, z1);
            z2 = fmaf(hall[e], u.z, z2); z3 = fmaf(hall[e], u.w, z3);
        }
        c = fmaf(sigm(z1), c, sigm(z0) * fmaxf(z2, 0.f));
        h = sigm(z3) * fmaxf(c, 0.f);
        barh[r] = h;
    }
    const double invN = 1.0 / ((double)B * 14.0);
    const float mean3 = (float)(stats3[d]     * invN);
    const float e32   = (float)(stats3[8 + d] * invN);
    const float a3 = gamma3[d] * rsqrtf(e32 - mean3*mean3 + EPSV);
    const float b3 = beta3[d] - mean3*a3;
    #pragma unroll
    for (int r = 0; r < 14; ++r) barh[r] = fmaf(barh[r], a3, b3);

    const int q = d & 3;
    const float* w2p = &lw2[q*36];
    const float* u2p = &lu2[q*20];
    float b2v[4];
    #pragma unroll
    for (int g = 0; g < 4; ++g) b2v[g] = b2[4*g + q];

    float ho = 0.f, co = 0.f;
    const size_t obase = ((size_t)blockIdx.x*32 + (tid >> 3)) * 56;
    #pragma unroll
    for (int r = 0; r < 14; ++r){
        const float cur = barh[13 - r];
        float be[8]; BC8_ALL(be, cur);
        float h4[4];
        h4[0]=bc8<0>(ho); h4[1]=bc8<1>(ho); h4[2]=bc8<2>(ho); h4[3]=bc8<3>(ho);
        float z0 = b2v[0], z1 = b2v[1], z2 = b2v[2], z3 = b2v[3];
        #pragma unroll
        for (int e = 0; e < 8; ++e){
            const float4 w = *reinterpret_cast<const float4*>(w2p + e*4);
            z0 = fmaf(be[e], w.x, z0); z1 = fmaf(be[e], w.y, z1);
            z2 = fmaf(be[e], w.z, z2); z3 = fmaf(be[e], w.w, z3);
        }
        #pragma unroll
        for (int e = 0; e < 4; ++e){
            const float4 u = *reinterpret_cast<const float4*>(u2p + e*4);
            z0 = fmaf(h4[e], u.x, z0); z1 = fmaf(h4[e], u.y, z1);
            z2 = fmaf(h4[e], u.z, z2); z3 = fmaf(h4[e], u.w, z3);
        }
        co = fmaf(sigm(z1), co, sigm(z0) * fmaxf(z2, 0.f));
        ho = sigm(z3) * fmaxf(co, 0.f);
        if (d < 4) out[obase + r*4 + d] = ho;
    }
}

extern "C" void kernel_launch(void* const* d_in, const int* in_sizes, int n_in,
                              void* d_out, int out_size, void* d_ws, size_t ws_size,
                              hipStream_t stream)
{
    const float* noise   = (const float*)d_in[0];
    const float* W0      = (const float*)d_in[1];
    const float* U0      = (const float*)d_in[2];
    const float* b0      = (const float*)d_in[3];
    const float* gamma_h = (const float*)d_in[4];
    const float* beta_h  = (const float*)d_in[5];
    const float* gamma_c = (const float*)d_in[6];
    const float* beta_c  = (const float*)d_in[7];
    const float* W1      = (const float*)d_in[8];
    const float* U1      = (const float*)d_in[9];
    const float* b1      = (const float*)d_in[10];
    const float* gamma3  = (const float*)d_in[11];
    const float* beta3   = (const float*)d_in[12];
    const float* W2      = (const float*)d_in[13];
    const float* U2      = (const float*)d_in[14];
    const float* b2      = (const float*)d_in[15];

    const int B = in_sizes[0] / (32 * 16);   // 65536
    double* stats1 = (double*)d_ws;          // 32 doubles
    double* stats3 = stats1 + 32;            // 16 doubles
    float* Hbuf = (float*)((char*)d_ws + 512);
    float* Cbuf = Hbuf + (size_t)B * 8;

    hipMemsetAsync(d_ws, 0, 48 * sizeof(double), stream);
    const int nb = B / 32;  // 2048 blocks x 256 threads
    k1_lstm0<<<nb, 256, 0, stream>>>(noise, W0, U0, b0, Hbuf, Cbuf, stats1);
    k2_ar<<<nb, 256, 0, stream>>>(Hbuf, Cbuf, stats1, gamma_h, beta_h, gamma_c, beta_c,
                                  W1, U1, b1, stats3, B);
    k3_out<<<nb, 256, 0, stream>>>(Hbuf, Cbuf, stats1, stats3, gamma_h, beta_h, gamma_c, beta_c,
                                   W1, U1, b1, gamma3, beta3, W2, U2, b2, (float*)d_out, B);
}